// Round 4
// baseline (386.337 us; speedup 1.0000x reference)
//
#include <hip/hip_runtime.h>
#include <hip/hip_bf16.h>

// B=8, C=64, N=65536 (all fp32 in/out).
// attn = 0.125 * Wv @ (X^T X) @ Wk^T  per batch (64x64)
// A = softmax(top50-mask(attn))  (emitted bf16 row-major)
// Q = X @ Wq^T  (bf16, computed in k1 alongside the Gram)
// out[n'=r*1024+t, :] = x[n',:] + bproj + Wproj @ (Q[64t..64t+63,:] @ A^T)
// MFMA: v_mfma_f32_16x16x32_bf16 (A[m=lane&15][k=q*8+j], B[n=lane&15][k=q*8+j],
// D[row=q*4+reg][col=lane&15]).
//
// R4 = R3 with the workspace-overlap bug fixed (G/a_bf/wpb previously landed
//      inside Qw at batch 4's offset; now explicit byte layout).

#define BATCHES 8
#define NROWS 65536
#define CDIM 64
#define BATCH_FLOATS (NROWS * CDIM)   // 4194304

typedef __attribute__((ext_vector_type(8))) short bf16x8;
typedef __attribute__((ext_vector_type(4))) float f32x4;

__device__ __forceinline__ short f2bf(float f) {
    union { __hip_bfloat16 h; short s; } u;
    u.h = __float2bfloat16(f);
    return u.s;
}
__device__ __forceinline__ unsigned int pk2(float a, float b) {
    return (unsigned int)(unsigned short)f2bf(a) |
           ((unsigned int)(unsigned short)f2bf(b) << 16);
}

__device__ __forceinline__ void fma16v(float a, const float4* p, float* acc) {
    float4 b0 = p[0], b1 = p[1], b2 = p[2], b3 = p[3];
    acc[0]  = fmaf(a, b0.x, acc[0]);  acc[1]  = fmaf(a, b0.y, acc[1]);
    acc[2]  = fmaf(a, b0.z, acc[2]);  acc[3]  = fmaf(a, b0.w, acc[3]);
    acc[4]  = fmaf(a, b1.x, acc[4]);  acc[5]  = fmaf(a, b1.y, acc[5]);
    acc[6]  = fmaf(a, b1.z, acc[6]);  acc[7]  = fmaf(a, b1.w, acc[7]);
    acc[8]  = fmaf(a, b2.x, acc[8]);  acc[9]  = fmaf(a, b2.y, acc[9]);
    acc[10] = fmaf(a, b2.z, acc[10]); acc[11] = fmaf(a, b2.w, acc[11]);
    acc[12] = fmaf(a, b3.x, acc[12]); acc[13] = fmaf(a, b3.y, acc[13]);
    acc[14] = fmaf(a, b3.z, acc[14]); acc[15] = fmaf(a, b3.w, acc[15]);
}

// ---------------- K1: Gram partials + Q = X@Wq^T (bf16) -------------------
// grid (64, 8), 256 threads (4 waves), 16 tiles of 64 rows per block.
// Staging: thread owns cols f = (tid&15)+16i, rows n0..n0+3. Same 16 scalar
// loads feed BOTH the X^T copy (Gram frags, 4x ds_write_b64 conflict-free)
// and the X row-major copy (Q frags, 16x ds_write_b16 ~2-way).
__global__ __launch_bounds__(256) void k1_gram(const float* __restrict__ x,
                                               const float* __restrict__ w_qkv,
                                               float* __restrict__ Gpart,
                                               ushort* __restrict__ Qw,
                                               int ntiles) {
    __shared__ __align__(16) short xt[2][64 * 72];  // X^T[f][n] bf16, stride 72
    __shared__ __align__(16) short xr[2][64 * 72];  // X[n][f]  bf16, stride 72
    int p = blockIdx.x, b = blockIdx.y;
    int tid = threadIdx.x;
    int l = tid & 63;
    int w = tid >> 6;
    int lm = l & 15, q = l >> 4;
    int n0 = 4 * (tid >> 4);     // row group (0..60)
    int c0 = tid & 15;           // col base  (0..15)
    const float* xb = x + (size_t)b * BATCH_FLOATS + (size_t)p * ntiles * 4096;
    ushort* Qb = Qw + (size_t)b * BATCH_FLOATS + (size_t)p * ntiles * 4096;

    // Wq B-frags: rows d = 16w+lm of w_qkv[0:64][:], bf16
    bf16x8 wqf[2];
#pragma unroll
    for (int ks = 0; ks < 2; ++ks) {
        const float* wp = w_qkv + (16 * w + lm) * 64 + ks * 32 + q * 8;
        float4 a0 = *(const float4*)wp, a1 = *(const float4*)(wp + 4);
        bf16x8 f;
        f[0] = f2bf(a0.x); f[1] = f2bf(a0.y); f[2] = f2bf(a0.z); f[3] = f2bf(a0.w);
        f[4] = f2bf(a1.x); f[5] = f2bf(a1.y); f[6] = f2bf(a1.z); f[7] = f2bf(a1.w);
        wqf[ks] = f;
    }

    f32x4 acc[4];
#pragma unroll
    for (int mi = 0; mi < 4; ++mi) acc[mi] = (f32x4){0.f, 0.f, 0.f, 0.f};

    float pre[4][4];             // pre[r][i] = X[n0+r][c0+16i]
#pragma unroll
    for (int r = 0; r < 4; ++r)
#pragma unroll
        for (int i = 0; i < 4; ++i)
            pre[r][i] = xb[(size_t)(n0 + r) * 64 + c0 + 16 * i];

    for (int tt = 0; tt < ntiles; ++tt) {
        short* buf = xt[tt & 1];
        short* bufr = xr[tt & 1];
#pragma unroll
        for (int i = 0; i < 4; ++i) {          // X^T: col f = c0+16i, rows n0..n0+3
            int f = c0 + 16 * i;
            uint2 pk;
            pk.x = pk2(pre[0][i], pre[1][i]);
            pk.y = pk2(pre[2][i], pre[3][i]);
            *(uint2*)&buf[f * 72 + n0] = pk;
#pragma unroll
            for (int r = 0; r < 4; ++r)        // X row-major for Q frags
                bufr[(n0 + r) * 72 + f] = f2bf(pre[r][i]);
        }
        if (tt + 1 < ntiles) {
            const float* nx = xb + (size_t)(tt + 1) * 4096;
#pragma unroll
            for (int r = 0; r < 4; ++r)
#pragma unroll
                for (int i = 0; i < 4; ++i)
                    pre[r][i] = nx[(size_t)(n0 + r) * 64 + c0 + 16 * i];
        }
        __syncthreads();   // double buffer: one barrier per tile
        // Gram: acc[mi] += XT-frags x XT-frags
        bf16x8 bfrag[2];
#pragma unroll
        for (int ks = 0; ks < 2; ++ks)
            bfrag[ks] = *(const bf16x8*)&buf[(16 * w + lm) * 72 + ks * 32 + q * 8];
#pragma unroll
        for (int mi = 0; mi < 4; ++mi) {
#pragma unroll
            for (int ks = 0; ks < 2; ++ks) {
                bf16x8 af = *(const bf16x8*)&buf[(mi * 16 + lm) * 72 + ks * 32 + q * 8];
                acc[mi] = __builtin_amdgcn_mfma_f32_16x16x32_bf16(af, bfrag[ks], acc[mi], 0, 0, 0);
            }
        }
        // Q tile: Q[p][d] = sum_e X[p][e] Wq[d][e]; store bf16 row-major
#pragma unroll
        for (int mi = 0; mi < 4; ++mi) {
            f32x4 aq = (f32x4){0.f, 0.f, 0.f, 0.f};
#pragma unroll
            for (int ks = 0; ks < 2; ++ks) {
                bf16x8 af = *(const bf16x8*)&bufr[(mi * 16 + lm) * 72 + ks * 32 + q * 8];
                aq = __builtin_amdgcn_mfma_f32_16x16x32_bf16(af, wqf[ks], aq, 0, 0, 0);
            }
            // aq[reg] = Q[tt*64 + mi*16 + q*4 + reg][16w+lm]
            ushort* qd = Qb + (size_t)(tt * 64 + mi * 16 + q * 4) * 64 + 16 * w + lm;
#pragma unroll
            for (int r = 0; r < 4; ++r)
                qd[r * 64] = (ushort)f2bf(aq[r]);
        }
    }
    float* Gp = Gpart + ((size_t)(b * 64 + p) << 12);
#pragma unroll
    for (int mi = 0; mi < 4; ++mi)
#pragma unroll
        for (int r = 0; r < 4; ++r)
            Gp[(mi * 16 + q * 4 + r) * 64 + 16 * w + lm] = acc[mi][r];
}

// ---------------- K1b: wide reduce of Gram partials -----------------------
// grid (16, 8), 256 threads: block sums 64 partials for 256 elements.
__global__ __launch_bounds__(256) void k1b_reduce(const float* __restrict__ Gpart,
                                                  float* __restrict__ G) {
    int b = blockIdx.y;
    int e = blockIdx.x * 256 + threadIdx.x;   // 0..4095
    const float* gp = Gpart + ((size_t)(b * 64) << 12) + e;
    float s = 0.f;
#pragma unroll 8
    for (int pp = 0; pp < 64; ++pp) s += gp[(size_t)pp << 12];
    G[b * 4096 + e] = s;
}

// ---------------- K2: attn, rank-count topk, softmax -> A (bf16) ----------
#define S68 68
__global__ __launch_bounds__(256) void k2_attn(const float* __restrict__ G,
                                               const float* __restrict__ w_qkv,
                                               const float* __restrict__ w_proj,
                                               ushort* __restrict__ a_bf,
                                               ushort* __restrict__ wpb) {
    __shared__ float A[64 * S68];   // G -> T1
    __shared__ float Bf[64 * S68];  // wkT -> attn
    __shared__ float Cf[64 * S68];  // wvT
    int b = blockIdx.x;
    int tid = threadIdx.x;
    int lane = tid & 63;
    int w = __builtin_amdgcn_readfirstlane(tid >> 6);

    // wpb slice: block b converts its 512 floats of Wproj to bf16
    if (tid < 128) {
        int idx = b * 128 + tid;
        float4 v = ((const float4*)w_proj)[idx];
        uint2 pp;
        pp.x = pk2(v.x, v.y);
        pp.y = pk2(v.z, v.w);
        *(uint2*)(wpb + 4 * idx) = pp;
    }

    {   // G -> A[c][f]
        const float4* g4 = (const float4*)(G + b * 4096);
#pragma unroll
        for (int u = 0; u < 4; ++u) {
            int idx = u * 256 + tid;
            int c = idx >> 4, f = (idx & 15) * 4;
            float4 g = g4[idx];
            A[c * S68 + f + 0] = g.x; A[c * S68 + f + 1] = g.y;
            A[c * S68 + f + 2] = g.z; A[c * S68 + f + 3] = g.w;
        }
    }
#pragma unroll
    for (int u = 0; u < 4; ++u) {   // wkT, wvT (transposed, stride 68)
        int idx = u * 256 + tid;
        int d = idx >> 4, f = (idx & 15) * 4;
        float4 kv = ((const float4*)(w_qkv + 64 * 64))[idx];
        Bf[(f + 0) * S68 + d] = kv.x; Bf[(f + 1) * S68 + d] = kv.y;
        Bf[(f + 2) * S68 + d] = kv.z; Bf[(f + 3) * S68 + d] = kv.w;
        float4 vv = ((const float4*)(w_qkv + 128 * 64))[idx];
        Cf[(f + 0) * S68 + d] = vv.x; Cf[(f + 1) * S68 + d] = vv.y;
        Cf[(f + 2) * S68 + d] = vv.z; Cf[(f + 3) * S68 + d] = vv.w;
    }
    __syncthreads();

    // T1[e][d] = sum_f G[e][f] Wk[d][f]  (G symmetric: read G[f][e])
    float acc[16];
#pragma unroll
    for (int k = 0; k < 16; ++k) acc[k] = 0.f;
    for (int f = 0; f < 64; ++f)
        fma16v(A[f * S68 + lane], (const float4*)&Bf[f * S68 + 16 * w], acc);
    __syncthreads();
#pragma unroll
    for (int k = 0; k < 16; ++k) A[lane * S68 + 16 * w + k] = acc[k];  // T1[e][d]
    __syncthreads();

    // attn[c][d] = 0.125 * sum_e Wv[c][e] T1[e][d]
#pragma unroll
    for (int k = 0; k < 16; ++k) acc[k] = 0.f;
    for (int e = 0; e < 64; ++e)
        fma16v(Cf[e * S68 + lane], (const float4*)&A[e * S68 + 16 * w], acc);
#pragma unroll
    for (int k = 0; k < 16; ++k) Bf[lane * S68 + 16 * w + k] = acc[k] * 0.125f; // ROW-major attn
    __syncthreads();

    // top-50 by rank count + softmax; emit A row-major bf16 directly
    ushort* ab = a_bf + (size_t)b * 4096;
#pragma unroll 1
    for (int k = 0; k < 16; ++k) {
        int c = 16 * w + k;
        float v = Bf[c * S68 + lane];
        int rank = 0;
#pragma unroll
        for (int d4 = 0; d4 < 16; ++d4) {
            float4 vv = *(const float4*)&Bf[c * S68 + 4 * d4];
            rank += (vv.x > v) || (vv.x == v && (4 * d4 + 0) < lane);
            rank += (vv.y > v) || (vv.y == v && (4 * d4 + 1) < lane);
            rank += (vv.z > v) || (vv.z == v && (4 * d4 + 2) < lane);
            rank += (vv.w > v) || (vv.w == v && (4 * d4 + 3) < lane);
        }
        bool act = rank < 50;
        float mv = act ? v : -INFINITY;
#pragma unroll
        for (int s = 1; s < 64; s <<= 1) mv = fmaxf(mv, __shfl_xor(mv, s, 64));
        float e = act ? expf(v - mv) : 0.f;
        float sum = e;
#pragma unroll
        for (int s = 1; s < 64; s <<= 1) sum += __shfl_xor(sum, s, 64);
        ab[c * 64 + lane] = (ushort)f2bf(e / sum);   // A[c][d=lane]
    }
}

// ---------------- K3: two MFMA GEMMs + residual epilogue (barrier-free) ---
// grid (1024, 8), 256 threads. A-frags straight from global Q (L1 absorbs
// the 4x wave redundancy); only LDS is the swizzled yyt handoff (same-wave).
__global__ __launch_bounds__(256) void k3_main(const float* __restrict__ x,
                                               const ushort* __restrict__ Qw,
                                               const ushort* __restrict__ a_bf,
                                               const ushort* __restrict__ wpb,
                                               const float* __restrict__ b_proj,
                                               float* __restrict__ out) {
    __shared__ __align__(16) short yyt[64 * 64];  // YY^T[r][p] bf16, swizzled
    int t = blockIdx.x, b = blockIdx.y;
    int tid = threadIdx.x;
    int l = tid & 63;
    int w = tid >> 6;
    int lm = l & 15, q = l >> 4;
    const float* xb = x + (size_t)b * BATCH_FLOATS;

    // --- prefetch residual x for the rows this lane will write -----------
    int rowbase = (16 * w + lm) * 1024 + t;       // out row n'
    const float* xr = xb + (size_t)rowbase * 64 + q * 4;
    float4 resid[4];
#pragma unroll
    for (int mi = 0; mi < 4; ++mi) resid[mi] = *(const float4*)(xr + mi * 16);

    // --- B1 frags: rows r = 16w+lm of A (bf16 global, L2-hot) ------------
    const ushort* ab = a_bf + (size_t)b * 4096;
    bf16x8 b1[2];
#pragma unroll
    for (int ks = 0; ks < 2; ++ks)
        b1[ks] = *(const bf16x8*)(ab + (16 * w + lm) * 64 + ks * 32 + q * 8);

    // --- GEMM1: YY[p][r] = sum_d Q[64t+p][d] A[r][d] ---------------------
    const ushort* Qt = Qw + (size_t)b * BATCH_FLOATS + (size_t)(64 * t) * 64;
    f32x4 acc1[4];
#pragma unroll
    for (int mi = 0; mi < 4; ++mi) {
        acc1[mi] = (f32x4){0.f, 0.f, 0.f, 0.f};
#pragma unroll
        for (int ks = 0; ks < 2; ++ks) {
            bf16x8 af = *(const bf16x8*)(Qt + (size_t)(mi * 16 + lm) * 64 + ks * 32 + q * 8);
            acc1[mi] = __builtin_amdgcn_mfma_f32_16x16x32_bf16(af, b1[ks], acc1[mi], 0, 0, 0);
        }
    }
    // write YY^T rows (this wave's own 16 r-rows), swizzled bf16
    {
        int r = 16 * w + lm;
#pragma unroll
        for (int mi = 0; mi < 4; ++mi) {
            uint2 p;
            p.x = pk2(acc1[mi][0], acc1[mi][1]);
            p.y = pk2(acc1[mi][2], acc1[mi][3]);
            int off = r * 128 + (((mi * 32) + (q * 8)) ^ ((r & 7) << 4));
            *(uint2*)((char*)yyt + off) = p;
        }
    }

    // --- GEMM2: OUT[j][r] = sum_p Wproj[j][p] YY[p][r] -------------------
    bf16x8 b2[2];
    {
        int r = 16 * w + lm;
#pragma unroll
        for (int ks = 0; ks < 2; ++ks)
            b2[ks] = *(const bf16x8*)((const char*)yyt + r * 128 +
                                      ((ks * 64 + q * 16) ^ ((r & 7) << 4)));
    }
    f32x4 acc2[4];
#pragma unroll
    for (int mi = 0; mi < 4; ++mi) {
        acc2[mi] = (f32x4){0.f, 0.f, 0.f, 0.f};
#pragma unroll
        for (int ks = 0; ks < 2; ++ks) {
            bf16x8 af = *(const bf16x8*)(wpb + (mi * 16 + lm) * 64 + ks * 32 + q * 8);
            acc2[mi] = __builtin_amdgcn_mfma_f32_16x16x32_bf16(af, b2[ks], acc2[mi], 0, 0, 0);
        }
    }

    // --- epilogue: direct store from acc2 layout -------------------------
    // acc2[mi][reg] = OUT[j = mi*16 + q*4 + reg][r = 16w+lm]
    float* ob = out + (size_t)b * BATCH_FLOATS + (size_t)rowbase * 64 + q * 4;
#pragma unroll
    for (int mi = 0; mi < 4; ++mi) {
        float4 bias = *(const float4*)(b_proj + mi * 16 + q * 4);
        float4 o;
        o.x = acc2[mi][0] + bias.x + resid[mi].x;
        o.y = acc2[mi][1] + bias.y + resid[mi].y;
        o.z = acc2[mi][2] + bias.z + resid[mi].z;
        o.w = acc2[mi][3] + bias.w + resid[mi].w;
        *(float4*)(ob + mi * 16) = o;
    }
}

extern "C" void kernel_launch(void* const* d_in, const int* in_sizes, int n_in,
                              void* d_out, int out_size, void* d_ws, size_t ws_size,
                              hipStream_t stream) {
    (void)in_sizes; (void)n_in; (void)out_size; (void)ws_size;
    const float* x      = (const float*)d_in[0];
    const float* w_qkv  = (const float*)d_in[1];
    const float* w_proj = (const float*)d_in[2];
    const float* b_proj = (const float*)d_in[3];
    float* out = (float*)d_out;
    char*  ws  = (char*)d_ws;

    // explicit byte layout (R3 bug: G overlapped Qw at batch-4 offset)
    float*  Gpart = (float*)(ws);                           // 8 MB   [0, 8M)
    ushort* Qw    = (ushort*)(ws + (8u << 20));             // 64 MB  [8M, 72M)
    float*  G     = (float*)(ws + (72u << 20));             // 128 KB [72M, ...)
    ushort* a_bf  = (ushort*)(ws + (72u << 20) + (128u << 10)); // 64 KB
    ushort* wpb   = a_bf + BATCHES * 4096;                  // 8 KB

    k1_gram<<<dim3(64, BATCHES), 256, 0, stream>>>(x, w_qkv, Gpart, Qw, 16);
    k1b_reduce<<<dim3(16, BATCHES), 256, 0, stream>>>(Gpart, G);
    k2_attn<<<BATCHES, 256, 0, stream>>>(G, w_qkv, w_proj, a_bf, wpb);
    k3_main<<<dim3(1024, BATCHES), 256, 0, stream>>>(x, Qw, a_bf, wpb, b_proj, out);
}

// Round 5
// 320.371 us; speedup vs baseline: 1.2059x; 1.2059x over previous
//
#include <hip/hip_runtime.h>
#include <hip/hip_bf16.h>

// B=8, C=64, N=65536 (all fp32 in/out).
// attn = 0.125 * Wv @ (X^T X) @ Wk^T  per batch (64x64)
// A = softmax(top50-mask(attn)); M = A @ Wq  (emitted bf16)
// out[n'=r*1024+t, :] = x[n',:] + bproj + Wproj @ (X[64t..64t+63,:] @ M[r,:])
// MFMA: v_mfma_f32_16x16x32_bf16 (A[m=lane&15][k=q*8+j], B[n=lane&15][k=q*8+j],
// D[row=q*4+reg][col=lane&15]).
//
// R5: revert Q-hoist (R4 regression: k3 went latency-bound at VGPR=40).
//     Best-known-good k1 (R2 staging) + wide k1b + R1 k3 verbatim.
//     NEW: k2 widened to 1024 threads (16 waves x 4 cols) -- the ~50us
//     serial-latency tail on 8 CUs cut 4x per-thread.

#define BATCHES 8
#define NROWS 65536
#define CDIM 64
#define BATCH_FLOATS (NROWS * CDIM)   // 4194304

typedef __attribute__((ext_vector_type(8))) short bf16x8;
typedef __attribute__((ext_vector_type(4))) float f32x4;

__device__ __forceinline__ short f2bf(float f) {
    union { __hip_bfloat16 h; short s; } u;
    u.h = __float2bfloat16(f);
    return u.s;
}
__device__ __forceinline__ unsigned int pk2(float a, float b) {
    return (unsigned int)(unsigned short)f2bf(a) |
           ((unsigned int)(unsigned short)f2bf(b) << 16);
}

// ---------------- K1: Gram via MFMA, per-block partials (no atomics) ------
// grid (64, 8), 256 threads (4 waves). Each block: 16 tiles of 64 rows.
// Staging: thread owns cols f = (tid&15)+16i, rows n0..n0+3 (n0=4*(tid>>4)).
//   16 scalar loads (coalesced: lanes 0-15 read 64 consecutive floats),
//   4 packed ds_write_b64 along n (inter-lane f-stride 144B -> ~2-way, free).
__global__ __launch_bounds__(256) void k1_gram(const float* __restrict__ x,
                                               float* __restrict__ Gpart,
                                               int ntiles) {
    __shared__ __align__(16) short xt[2][64 * 72];  // XT[f][n] bf16, stride 72
    int p = blockIdx.x, b = blockIdx.y;
    int tid = threadIdx.x;
    int l = tid & 63;
    int w = tid >> 6;
    int lm = l & 15, q = l >> 4;
    int n0 = 4 * (tid >> 4);     // row group (0..60)
    int c0 = tid & 15;           // col base  (0..15)
    const float* xb = x + (size_t)b * BATCH_FLOATS + (size_t)p * ntiles * 4096;

    f32x4 acc[4];
#pragma unroll
    for (int mi = 0; mi < 4; ++mi) acc[mi] = (f32x4){0.f, 0.f, 0.f, 0.f};

    float pre[4][4];             // pre[r][i] = X[n0+r][c0+16i]
#pragma unroll
    for (int r = 0; r < 4; ++r)
#pragma unroll
        for (int i = 0; i < 4; ++i)
            pre[r][i] = xb[(size_t)(n0 + r) * 64 + c0 + 16 * i];

    for (int tt = 0; tt < ntiles; ++tt) {
        short* buf = xt[tt & 1];
#pragma unroll
        for (int i = 0; i < 4; ++i) {          // write col f = c0+16i, rows n0..n0+3
            int f = c0 + 16 * i;
            uint2 pk;
            pk.x = pk2(pre[0][i], pre[1][i]);
            pk.y = pk2(pre[2][i], pre[3][i]);
            *(uint2*)&buf[f * 72 + n0] = pk;   // byte off = f*144 + n0*2 (8B aligned)
        }
        if (tt + 1 < ntiles) {
            const float* nx = xb + (size_t)(tt + 1) * 4096;
#pragma unroll
            for (int r = 0; r < 4; ++r)
#pragma unroll
                for (int i = 0; i < 4; ++i)
                    pre[r][i] = nx[(size_t)(n0 + r) * 64 + c0 + 16 * i];
        }
        __syncthreads();   // double buffer: one barrier per tile
        bf16x8 bfrag[2];
#pragma unroll
        for (int ks = 0; ks < 2; ++ks)
            bfrag[ks] = *(const bf16x8*)&buf[(16 * w + lm) * 72 + ks * 32 + q * 8];
#pragma unroll
        for (int mi = 0; mi < 4; ++mi) {
#pragma unroll
            for (int ks = 0; ks < 2; ++ks) {
                bf16x8 af = *(const bf16x8*)&buf[(mi * 16 + lm) * 72 + ks * 32 + q * 8];
                acc[mi] = __builtin_amdgcn_mfma_f32_16x16x32_bf16(af, bfrag[ks], acc[mi], 0, 0, 0);
            }
        }
    }
    // plain stores of this block's partial Gram (reduced in k1b)
    float* Gp = Gpart + ((size_t)(b * 64 + p) << 12);
#pragma unroll
    for (int mi = 0; mi < 4; ++mi)
#pragma unroll
        for (int r = 0; r < 4; ++r)
            Gp[(mi * 16 + q * 4 + r) * 64 + 16 * w + lm] = acc[mi][r];
}

// ---------------- K1b: wide reduce of Gram partials -----------------------
// grid (16, 8), 256 threads: block sums 64 partials for 256 elements.
__global__ __launch_bounds__(256) void k1b_reduce(const float* __restrict__ Gpart,
                                                  float* __restrict__ G) {
    int b = blockIdx.y;
    int e = blockIdx.x * 256 + threadIdx.x;   // 0..4095
    const float* gp = Gpart + ((size_t)(b * 64) << 12) + e;
    float s = 0.f;
#pragma unroll 8
    for (int pp = 0; pp < 64; ++pp) s += gp[(size_t)pp << 12];
    G[b * 4096 + e] = s;
}

// ---------------- K2: attn, rank-count topk, softmax, M(bf16) -------------
// 1024 threads (16 waves): wave wg owns 4 columns / 4 topk rows. 4x less
// serial per-thread work than the 256-thread version (the latency tail).
#define S68 68
__global__ __launch_bounds__(1024) void k2_attn(const float* __restrict__ G,
                                                const float* __restrict__ w_qkv,
                                                const float* __restrict__ w_proj,
                                                ushort* __restrict__ m_bf,
                                                ushort* __restrict__ wpb) {
    __shared__ float A[64 * S68];   // G -> T1
    __shared__ float Bf[64 * S68];  // wkT -> attn
    __shared__ float Cf[64 * S68];  // wvT -> AT
    int b = blockIdx.x;
    int tid = threadIdx.x;          // 0..1023
    int lane = tid & 63;
    int wg = tid >> 6;              // 0..15

    // wpb slice: block b converts its 512 floats of Wproj to bf16
    if (tid < 128) {
        int idx = b * 128 + tid;
        float4 v = ((const float4*)w_proj)[idx];
        uint2 pp;
        pp.x = pk2(v.x, v.y);
        pp.y = pk2(v.z, v.w);
        *(uint2*)(wpb + 4 * idx) = pp;
    }

    {   // G -> A[c][f]   (1024 float4 = whole 64x64, one per thread)
        int idx = tid;
        int c = idx >> 4, f = (idx & 15) * 4;
        float4 g = ((const float4*)(G + b * 4096))[idx];
        A[c * S68 + f + 0] = g.x; A[c * S68 + f + 1] = g.y;
        A[c * S68 + f + 2] = g.z; A[c * S68 + f + 3] = g.w;
        // wkT, wvT (transposed, stride 68)
        int d = idx >> 4;
        float4 kv = ((const float4*)(w_qkv + 64 * 64))[idx];
        Bf[(f + 0) * S68 + d] = kv.x; Bf[(f + 1) * S68 + d] = kv.y;
        Bf[(f + 2) * S68 + d] = kv.z; Bf[(f + 3) * S68 + d] = kv.w;
        float4 vv = ((const float4*)(w_qkv + 128 * 64))[idx];
        Cf[(f + 0) * S68 + d] = vv.x; Cf[(f + 1) * S68 + d] = vv.y;
        Cf[(f + 2) * S68 + d] = vv.z; Cf[(f + 3) * S68 + d] = vv.w;
    }
    __syncthreads();

    // T1[e][d] = sum_f G[e][f] Wk[d][f]  (G symmetric: read G[f][e])
    // e = lane, d = 4*wg + j
    float acc[4] = {0.f, 0.f, 0.f, 0.f};
    for (int f = 0; f < 64; ++f) {
        float a = A[f * S68 + lane];
        float4 bv = *(const float4*)&Bf[f * S68 + 4 * wg];   // wave-broadcast
        acc[0] = fmaf(a, bv.x, acc[0]);
        acc[1] = fmaf(a, bv.y, acc[1]);
        acc[2] = fmaf(a, bv.z, acc[2]);
        acc[3] = fmaf(a, bv.w, acc[3]);
    }
    __syncthreads();
    *(float4*)&A[lane * S68 + 4 * wg] = make_float4(acc[0], acc[1], acc[2], acc[3]); // T1[e][d]
    __syncthreads();

    // attn[c][d] = 0.125 * sum_e Wv[c][e] T1[e][d];  c = lane, d = 4*wg + j
    acc[0] = acc[1] = acc[2] = acc[3] = 0.f;
    for (int e = 0; e < 64; ++e) {
        float a = Cf[e * S68 + lane];
        float4 bv = *(const float4*)&A[e * S68 + 4 * wg];    // wave-broadcast
        acc[0] = fmaf(a, bv.x, acc[0]);
        acc[1] = fmaf(a, bv.y, acc[1]);
        acc[2] = fmaf(a, bv.z, acc[2]);
        acc[3] = fmaf(a, bv.w, acc[3]);
    }
    *(float4*)&Bf[lane * S68 + 4 * wg] = make_float4(acc[0] * 0.125f, acc[1] * 0.125f,
                                                     acc[2] * 0.125f, acc[3] * 0.125f);
    __syncthreads();

    // top-50 by rank count + softmax; write AT[d][c] -> Cf.  Wave wg: rows 4wg..4wg+3
#pragma unroll
    for (int k = 0; k < 4; ++k) {
        int c = 4 * wg + k;
        float v = Bf[c * S68 + lane];
        int rank = 0;
#pragma unroll
        for (int d4 = 0; d4 < 16; ++d4) {
            float4 vv = *(const float4*)&Bf[c * S68 + 4 * d4];
            rank += (vv.x > v) || (vv.x == v && (4 * d4 + 0) < lane);
            rank += (vv.y > v) || (vv.y == v && (4 * d4 + 1) < lane);
            rank += (vv.z > v) || (vv.z == v && (4 * d4 + 2) < lane);
            rank += (vv.w > v) || (vv.w == v && (4 * d4 + 3) < lane);
        }
        bool act = rank < 50;
        float mv = act ? v : -INFINITY;
#pragma unroll
        for (int s = 1; s < 64; s <<= 1) mv = fmaxf(mv, __shfl_xor(mv, s, 64));
        float e = act ? expf(v - mv) : 0.f;
        float sum = e;
#pragma unroll
        for (int s = 1; s < 64; s <<= 1) sum += __shfl_xor(sum, s, 64);
        Cf[lane * S68 + c] = e / sum;          // AT[d=lane][c]
    }
    __syncthreads();

    // M[c][e] = sum_d A[c][d] Wq[d][e];  c = lane, e = 4*wg + j
    acc[0] = acc[1] = acc[2] = acc[3] = 0.f;
    for (int d = 0; d < 64; ++d) {
        float a = Cf[d * S68 + lane];
        float4 wv4 = *(const float4*)(w_qkv + d * 64 + 4 * wg);   // L1-hot broadcast
        acc[0] = fmaf(a, wv4.x, acc[0]);
        acc[1] = fmaf(a, wv4.y, acc[1]);
        acc[2] = fmaf(a, wv4.z, acc[2]);
        acc[3] = fmaf(a, wv4.w, acc[3]);
    }
    uint2 pp;
    pp.x = pk2(acc[0], acc[1]);
    pp.y = pk2(acc[2], acc[3]);
    *(uint2*)(m_bf + (size_t)b * 4096 + lane * 64 + 4 * wg) = pp;  // M[c][e] row-major
}

// ---------------- K3: two MFMA GEMMs + residual epilogue (R1 verbatim) ----
// grid (1024, 8), 256 threads. Xc staged once (swizzled bf16); resid + M
// prefetched; epilogue stores straight from acc2 layout; 1 barrier.
__global__ __launch_bounds__(256) void k3_main(const float* __restrict__ x,
                                               const ushort* __restrict__ m_bf,
                                               const ushort* __restrict__ wpb,
                                               const float* __restrict__ b_proj,
                                               float* __restrict__ out) {
    __shared__ __align__(16) short xt[64 * 64];   // Xc tile bf16, swizzled rows
    __shared__ __align__(16) short yyt[64 * 64];  // YY^T[r][p] bf16, swizzled
    int t = blockIdx.x, b = blockIdx.y;
    int tid = threadIdx.x;
    int l = tid & 63;
    int w = tid >> 6;
    int lm = l & 15, q = l >> 4;
    const float* xb = x + (size_t)b * BATCH_FLOATS;

    // --- prefetch residual x for the rows this lane will write -----------
    int rowbase = (16 * w + lm) * 1024 + t;       // out row n'
    const float* xr = xb + (size_t)rowbase * 64 + q * 4;
    float4 resid[4];
#pragma unroll
    for (int mi = 0; mi < 4; ++mi) resid[mi] = *(const float4*)(xr + mi * 16);

    // --- prefetch B1 frags (rows of M, bf16 global, L2-hot) --------------
    const ushort* mb = m_bf + (size_t)b * 4096;
    bf16x8 b1[2];
#pragma unroll
    for (int ks = 0; ks < 2; ++ks)
        b1[ks] = *(const bf16x8*)(mb + (16 * w + lm) * 64 + ks * 32 + q * 8);

    // --- stage Xc tile -> LDS bf16, swizzled, coalesced ------------------
    {
        const float4* s = (const float4*)(xb + (size_t)(64 * t) * 64);
#pragma unroll
        for (int u = 0; u < 4; ++u) {
            float4 v = s[u * 256 + tid];
            int row = u * 16 + (tid >> 4);
            int colb = (tid & 15) * 8;            // byte offset in row (4 bf16)
            int off = row * 128 + (colb ^ ((row & 7) << 4));
            uint2 p;
            p.x = pk2(v.x, v.y);
            p.y = pk2(v.z, v.w);
            *(uint2*)((char*)xt + off) = p;
        }
    }
    __syncthreads();

    // --- GEMM1: YY[p][r] = sum_e Xc[p][e] M[r][e] ------------------------
    f32x4 acc1[4];
#pragma unroll
    for (int mi = 0; mi < 4; ++mi) {
        acc1[mi] = (f32x4){0.f, 0.f, 0.f, 0.f};
#pragma unroll
        for (int ks = 0; ks < 2; ++ks) {
            int row = mi * 16 + lm;               // row&7 == lm&7
            bf16x8 af = *(const bf16x8*)((const char*)xt + row * 128 +
                                         ((ks * 64 + q * 16) ^ ((lm & 7) << 4)));
            acc1[mi] = __builtin_amdgcn_mfma_f32_16x16x32_bf16(af, b1[ks], acc1[mi], 0, 0, 0);
        }
    }
    // write YY^T rows (this wave's own 16 r-rows), swizzled bf16
    {
        int r = 16 * w + lm;
#pragma unroll
        for (int mi = 0; mi < 4; ++mi) {
            uint2 p;
            p.x = pk2(acc1[mi][0], acc1[mi][1]);
            p.y = pk2(acc1[mi][2], acc1[mi][3]);
            int off = r * 128 + (((mi * 32) + (q * 8)) ^ ((r & 7) << 4));
            *(uint2*)((char*)yyt + off) = p;
        }
    }

    // --- GEMM2: OUT[j][r] = sum_p Wproj[j][p] YY[p][r] -------------------
    bf16x8 b2[2];
    {
        int r = 16 * w + lm;
#pragma unroll
        for (int ks = 0; ks < 2; ++ks)
            b2[ks] = *(const bf16x8*)((const char*)yyt + r * 128 +
                                      ((ks * 64 + q * 16) ^ ((r & 7) << 4)));
    }
    f32x4 acc2[4];
#pragma unroll
    for (int mi = 0; mi < 4; ++mi) {
        acc2[mi] = (f32x4){0.f, 0.f, 0.f, 0.f};
#pragma unroll
        for (int ks = 0; ks < 2; ++ks) {
            bf16x8 af = *(const bf16x8*)(wpb + (mi * 16 + lm) * 64 + ks * 32 + q * 8);
            acc2[mi] = __builtin_amdgcn_mfma_f32_16x16x32_bf16(af, b2[ks], acc2[mi], 0, 0, 0);
        }
    }

    // --- epilogue: direct store from acc2 layout -------------------------
    // acc2[mi][reg] = OUT[j = mi*16 + q*4 + reg][r = 16w+lm]
    float* ob = out + (size_t)b * BATCH_FLOATS + (size_t)rowbase * 64 + q * 4;
#pragma unroll
    for (int mi = 0; mi < 4; ++mi) {
        float4 bias = *(const float4*)(b_proj + mi * 16 + q * 4);
        float4 o;
        o.x = acc2[mi][0] + bias.x + resid[mi].x;
        o.y = acc2[mi][1] + bias.y + resid[mi].y;
        o.z = acc2[mi][2] + bias.z + resid[mi].z;
        o.w = acc2[mi][3] + bias.w + resid[mi].w;
        *(float4*)(ob + mi * 16) = o;
    }
}

extern "C" void kernel_launch(void* const* d_in, const int* in_sizes, int n_in,
                              void* d_out, int out_size, void* d_ws, size_t ws_size,
                              hipStream_t stream) {
    (void)in_sizes; (void)n_in; (void)out_size; (void)ws_size;
    const float* x      = (const float*)d_in[0];
    const float* w_qkv  = (const float*)d_in[1];
    const float* w_proj = (const float*)d_in[2];
    const float* b_proj = (const float*)d_in[3];
    float* out = (float*)d_out;
    char*  ws  = (char*)d_ws;

    // explicit byte layout, no overlaps
    float*  Gpart = (float*)(ws);                               // 8 MB   [0, 8M)
    float*  G     = (float*)(ws + (8u << 20));                  // 128 KB
    ushort* m_bf  = (ushort*)(ws + (8u << 20) + (128u << 10));  // 64 KB
    ushort* wpb   = m_bf + BATCHES * 4096;                      // 8 KB

    k1_gram<<<dim3(64, BATCHES), 256, 0, stream>>>(x, Gpart, 16);
    k1b_reduce<<<dim3(16, BATCHES), 256, 0, stream>>>(Gpart, G);
    k2_attn<<<BATCHES, 1024, 0, stream>>>(G, w_qkv, w_proj, m_bf, wpb);
    k3_main<<<dim3(1024, BATCHES), 256, 0, stream>>>(x, m_bf, wpb, b_proj, out);
}